// Round 9
// baseline (322.751 us; speedup 1.0000x reference)
//
#include <hip/hip_runtime.h>
#include <stdint.h>

typedef unsigned short ushort_t;
typedef __bf16 bf16x8 __attribute__((ext_vector_type(8)));
typedef float f32x4 __attribute__((ext_vector_type(4)));

#define M_TOK 8192
#define K1 1024
#define N1 4096
#define K2 4160   /* 4096 (h) + 16 (probs/b2) + 48 zero-pad */
#define N2 1024

template <int V> struct ic { static constexpr int value = V; };

__device__ __forceinline__ ushort_t f2bf(float f) {
  union { float f; unsigned u; } v; v.f = f;
  unsigned u = v.u;
  u += 0x7FFFu + ((u >> 16) & 1u);   // RNE; inputs finite
  return (ushort_t)(u >> 16);
}

__device__ __forceinline__ void gload16(const void* g, void* l) {
  __builtin_amdgcn_global_load_lds((__attribute__((address_space(1))) void*)g,
                                   (__attribute__((address_space(3))) void*)l,
                                   16, 0, 0);
}

// ---------------- merged prep: wprep (blocks 0..2303) + probs (2304..4351) --
__global__ __launch_bounds__(256) void k_prep(
    const float* __restrict__ x, const float* __restrict__ node_w,
    const float* __restrict__ node_b, const float* __restrict__ w1,
    const float* __restrict__ w2, const float* __restrict__ b2,
    ushort_t* __restrict__ xb, float* __restrict__ probs,
    ushort_t* __restrict__ w1t, ushort_t* __restrict__ w2t,
    ushort_t* __restrict__ hp) {
  __shared__ ushort_t tile[64][68];
  const int b = blockIdx.x;
  if (b < 1024) {
    // w1t[l*256+h][k] = w1[l][k][h]
    const int tr = threadIdx.x >> 4, tc = (threadIdx.x & 15) * 4;
    const int l = b >> 6, rem = b & 63;
    const int kt = rem >> 2, ht = rem & 3;
    const float* in = w1 + (size_t)l * K1 * 256;
#pragma unroll
    for (int rr = 0; rr < 4; ++rr) {
      int r = tr + rr * 16;
      float4 v = *(const float4*)(in + (size_t)(kt * 64 + r) * 256 + ht * 64 + tc);
      tile[r][tc+0] = f2bf(v.x); tile[r][tc+1] = f2bf(v.y);
      tile[r][tc+2] = f2bf(v.z); tile[r][tc+3] = f2bf(v.w);
    }
    __syncthreads();
#pragma unroll
    for (int rr = 0; rr < 4; ++rr) {
      int oh = tr + rr * 16;
      ushort4 o;
      o.x = tile[tc+0][oh]; o.y = tile[tc+1][oh];
      o.z = tile[tc+2][oh]; o.w = tile[tc+3][oh];
      *(ushort4*)(w1t + (size_t)(l * 256 + ht * 64 + oh) * K1 + kt * 64 + tc) = o;
    }
  } else if (b < 2048) {
    // w2t[d][l*256+h] = w2[l][h][d]
    const int tr = threadIdx.x >> 4, tc = (threadIdx.x & 15) * 4;
    const int bb = b - 1024;
    const int l = bb >> 6, rem = bb & 63;
    const int ht = rem >> 4, dt = rem & 15;
    const float* in = w2 + (size_t)l * 256 * N2;
#pragma unroll
    for (int rr = 0; rr < 4; ++rr) {
      int r = tr + rr * 16;
      float4 v = *(const float4*)(in + (size_t)(ht * 64 + r) * N2 + dt * 64 + tc);
      tile[r][tc+0] = f2bf(v.x); tile[r][tc+1] = f2bf(v.y);
      tile[r][tc+2] = f2bf(v.z); tile[r][tc+3] = f2bf(v.w);
    }
    __syncthreads();
#pragma unroll
    for (int rr = 0; rr < 4; ++rr) {
      int od = tr + rr * 16;
      ushort4 o;
      o.x = tile[tc+0][od]; o.y = tile[tc+1][od];
      o.z = tile[tc+2][od]; o.w = tile[tc+3][od];
      *(ushort4*)(w2t + (size_t)(dt * 64 + od) * K2 + l * 256 + ht * 64 + tc) = o;
    }
  } else if (b < 2304) {
    int tid = (b - 2048) * 256 + threadIdx.x;   // 1024 * 64
    int d = tid >> 6, cc = tid & 63;
    float v = (cc < 16) ? b2[cc * N2 + d] : 0.f;
    w2t[(size_t)d * K2 + 4096 + cc] = f2bf(v);
  } else {
    // probs + x->bf16; 1 wave per token
    const int wid = threadIdx.x >> 6, lane = threadIdx.x & 63;
    const int t = (b - 2304) * 4 + wid;
    const float* xr = x + (size_t)t * K1;
    float xv[16];
#pragma unroll
    for (int j = 0; j < 4; ++j) {
      float4 v = *(const float4*)(xr + j * 256 + lane * 4);
      xv[4*j+0] = v.x; xv[4*j+1] = v.y; xv[4*j+2] = v.z; xv[4*j+3] = v.w;
    }
    ushort_t* xbr = xb + (size_t)t * K1;
#pragma unroll
    for (int j = 0; j < 4; ++j) {
      ushort4 o;
      o.x = f2bf(xv[4*j+0]); o.y = f2bf(xv[4*j+1]);
      o.z = f2bf(xv[4*j+2]); o.w = f2bf(xv[4*j+3]);
      *(ushort4*)(xbr + j * 256 + lane * 4) = o;
    }
    float c[15];
#pragma unroll
    for (int n = 0; n < 15; ++n) {
      float s = 0.f;
      const float* wr = node_w + n * K1;
#pragma unroll
      for (int j = 0; j < 4; ++j) {
        float4 w = *(const float4*)(wr + j * 256 + lane * 4);
        s += xv[4*j+0]*w.x + xv[4*j+1]*w.y + xv[4*j+2]*w.z + xv[4*j+3]*w.w;
      }
#pragma unroll
      for (int off = 32; off > 0; off >>= 1) s += __shfl_xor(s, off);
      float z = s + node_b[n];
      c[n] = 1.f / (1.f + __expf(-z));
    }
    if (lane < 16) {
      float p = 1.f;
#pragma unroll
      for (int m = 0; m < 4; ++m) {
        int jm = lane >> (4 - m);
        int node = (1 << m) - 1 + jm;
        int bit = (lane >> (3 - m)) & 1;
        p *= bit ? (1.f - c[node]) : c[node];
      }
      probs[t * 16 + lane] = p;
      hp[(size_t)t * K2 + 4096 + lane] = f2bf(p);
    }
    if (lane < 48) hp[(size_t)t * K2 + 4112 + lane] = 0;
  }
}

// ---- 256xBN GEMM, 4 waves (2Mx2N, per-wave 128x(BN/2)), BK=64, 2-buf LDS ---
// Per K-tile (ONE barrier): [stage(t+1 -> buf^1); reads(t, buf); MFMA burst;
// vmcnt(0); s_barrier]. Stage-early: the 12-16 gloads issue ~2500 cy before
// the vmcnt(0) drain -> drain is free. Hazards: stage targets buf^1, whose
// tile-(t-1) reads were consumed before the barrier just crossed; staging
// publication enforced by vmcnt(0)+barrier before tile t+1's reads.
// 4 waves halve LDS fragment-read amplification vs 8 waves (traffic
// = BK*2B*(WN*BM+WM*BN) = 128 KB vs 192 KB per K-tile) -> LDS time ~2260 cy
// vs per-SIMD MFMA 2480 cy: compute-balanced instead of LDS-dominated.
template <int NT, int LDA, int LDB, int BN, int MODE>
__global__ __launch_bounds__(256, 1) void k_gemm4(
    const ushort_t* __restrict__ A, const ushort_t* __restrict__ Bt,
    const float* __restrict__ probs, const float* __restrict__ b1,
    ushort_t* __restrict__ hp, float* __restrict__ out, int ntn) {
  constexpr int FN = BN / 32;                 // n-frags per wave (8|4)
  constexpr int ATILE = 256 * 128;            // 32 KB
  constexpr int BTILE = BN * 128;             // 32|16 KB
  constexpr int TB = ATILE + BTILE;
  constexpr int SA = ATILE / (256 * 16);      // 8 gloads/thread for A
  constexpr int SB = BTILE / (256 * 16);      // 8|4 for B

  extern __shared__ char lds[];
  const int tid = threadIdx.x;
  int bid = blockIdx.x;
  const int nwg = gridDim.x;                  // divisible by 8
  bid = (bid & 7) * (nwg >> 3) + (bid >> 3);  // XCD swizzle (bijective)
  const int bm = bid / ntn, bn = bid % ntn;

  const int wid = tid >> 6, lane = tid & 63;
  const int widM = wid >> 1, widN = wid & 1;  // 2M x 2N
  const int lr = lane & 15, g = lane >> 4;

  const ushort_t* Ag = A + (size_t)bm * 256 * LDA;
  const ushort_t* Bg = Bt + (size_t)bn * BN * LDB;

  // stage: slot s -> row=s>>3, 16B-slot=s&7; source col pre-XOR'd by row&7
  auto stage = [&](char* base, int kt) {
#pragma unroll
    for (int r = 0; r < SA; ++r) {
      int s = tid + r * 256;
      int row = s >> 3;
      int c16 = (s & 7) ^ (row & 7);
      gload16((const char*)(Ag + (size_t)row * LDA) + kt * 128 + (c16 << 4),
              base + s * 16);
    }
#pragma unroll
    for (int r = 0; r < SB; ++r) {
      int s = tid + r * 256;
      int row = s >> 3;
      int c16 = (s & 7) ^ (row & 7);
      gload16((const char*)(Bg + (size_t)row * LDB) + kt * 128 + (c16 << 4),
              base + ATILE + s * 16);
    }
  };
  auto rdA = [&](char* base, int mi, int kk) -> bf16x8 {
    int row = widM * 128 + mi * 16 + lr;
    return *(const bf16x8*)(base + row * 128 + (((kk * 4 + g) ^ (lr & 7)) << 4));
  };
  auto rdB = [&](char* base, int nj, int kk) -> bf16x8 {
    int row = widN * (BN / 2) + nj * 16 + lr;
    return *(const bf16x8*)(base + ATILE + row * 128 + (((kk * 4 + g) ^ (lr & 7)) << 4));
  };

  f32x4 acc[8][FN];
#pragma unroll
  for (int i = 0; i < 8; ++i)
#pragma unroll
    for (int j = 0; j < FN; ++j) acc[i][j] = (f32x4){0.f, 0.f, 0.f, 0.f};

  // prologue: tile0 -> buf0, drain, barrier.
  stage(lds, 0);
  asm volatile("s_waitcnt vmcnt(0)" ::: "memory");
  __builtin_amdgcn_sched_barrier(0);
  __builtin_amdgcn_s_barrier();
  __builtin_amdgcn_sched_barrier(0);

  auto body = [&](auto CURC, int kt) {
    constexpr int cur = decltype(CURC)::value;
    char* buf = lds + cur * TB;
    char* nbuf = lds + (cur ^ 1) * TB;
    if (kt + 1 < NT) stage(nbuf, kt + 1);
    __builtin_amdgcn_sched_barrier(0);
    bf16x8 a[8][2], b[FN][2];
#pragma unroll
    for (int kk = 0; kk < 2; ++kk) {
#pragma unroll
      for (int mi = 0; mi < 8; ++mi) a[mi][kk] = rdA(buf, mi, kk);
#pragma unroll
      for (int nj = 0; nj < FN; ++nj) b[nj][kk] = rdB(buf, nj, kk);
    }
#pragma unroll
    for (int kk = 0; kk < 2; ++kk)
#pragma unroll
      for (int nj = 0; nj < FN; ++nj)
#pragma unroll
        for (int mi = 0; mi < 8; ++mi)
          acc[mi][nj] = __builtin_amdgcn_mfma_f32_16x16x32_bf16(
              a[mi][kk], b[nj][kk], acc[mi][nj], 0, 0, 0);
    asm volatile("s_waitcnt vmcnt(0)" ::: "memory");
    __builtin_amdgcn_sched_barrier(0);
    __builtin_amdgcn_s_barrier();
    __builtin_amdgcn_sched_barrier(0);
  };

  int kt = 0;
#pragma unroll 1
  for (int it = 0; it < NT / 2; ++it) {
    body(ic<0>{}, kt); ++kt;
    body(ic<1>{}, kt); ++kt;
  }
  if constexpr (NT & 1) body(ic<0>{}, kt);

  // epilogue: C/D layout col=lane&15, row=(lane>>4)*4+reg
  const int rowb = bm * 256 + widM * 128 + g * 4;
  const int colb = bn * BN + widN * (BN / 2) + lr;
  if (MODE == 0) {
    const int leaf = bn;   // BN=256 tile == one leaf
#pragma unroll
    for (int mi = 0; mi < 8; ++mi) {
      int rbase = rowb + mi * 16;
      float pm[4];
#pragma unroll
      for (int rg = 0; rg < 4; ++rg)
        pm[rg] = probs[(size_t)(rbase + rg) * 16 + leaf];
#pragma unroll
      for (int nj = 0; nj < FN; ++nj) {
        float bias = b1[colb + nj * 16];
#pragma unroll
        for (int rg = 0; rg < 4; ++rg) {
          float v = acc[mi][nj][rg] + bias;
          v = v > 0.f ? v : 0.f;
          v *= pm[rg];
          hp[(size_t)(rbase + rg) * K2 + colb + nj * 16] = f2bf(v);
        }
      }
    }
  } else {
#pragma unroll
    for (int mi = 0; mi < 8; ++mi) {
      int rbase = rowb + mi * 16;
#pragma unroll
      for (int nj = 0; nj < FN; ++nj)
#pragma unroll
        for (int rg = 0; rg < 4; ++rg)
          out[(size_t)(rbase + rg) * N2 + colb + nj * 16] = acc[mi][nj][rg];
    }
  }
}

extern "C" void kernel_launch(void* const* d_in, const int* in_sizes, int n_in,
                              void* d_out, int out_size, void* d_ws, size_t ws_size,
                              hipStream_t stream) {
  const float* x      = (const float*)d_in[0];
  const float* node_w = (const float*)d_in[1];
  const float* node_b = (const float*)d_in[2];
  const float* w1     = (const float*)d_in[3];
  const float* b1     = (const float*)d_in[4];
  const float* w2     = (const float*)d_in[5];
  const float* b2     = (const float*)d_in[6];
  float* out = (float*)d_out;

  char* ws = (char*)d_ws;
  ushort_t* xb    = (ushort_t*)(ws);
  ushort_t* w1t   = (ushort_t*)(ws + 16777216);
  ushort_t* w2t   = (ushort_t*)(ws + 25165824);
  ushort_t* hp    = (ushort_t*)(ws + 33685504);
  float*    probs = (float*)   (ws + 101842944);

  k_prep<<<4352, 256, 0, stream>>>(x, node_w, node_b, w1, w2, b2,
                                   xb, probs, w1t, w2t, hp);
  // GEMM1: 8192x4096 K=1024: BM=BN=256, 32x16=512 blocks, 4 waves,
  // LDS 128 KiB (2-buf), per-wave 128x128
  k_gemm4<16, K1, K1, 256, 0><<<512, 256, 131072, stream>>>(
      xb, w1t, probs, b1, hp, nullptr, N1 / 256);
  // GEMM2: 8192x1024 K=4160: BM=256 BN=128, 32x8=256 blocks (1/CU), 4 waves,
  // LDS 96 KiB (2-buf), per-wave 128x64
  k_gemm4<65, K2, K2, 128, 1><<<256, 256, 98304, stream>>>(
      hp, w2t, nullptr, nullptr, nullptr, out, N2 / 128);
}

// Round 10
// 252.427 us; speedup vs baseline: 1.2786x; 1.2786x over previous
//
#include <hip/hip_runtime.h>
#include <stdint.h>

typedef unsigned short ushort_t;
typedef __bf16 bf16x8 __attribute__((ext_vector_type(8)));
typedef float f32x4 __attribute__((ext_vector_type(4)));

#define M_TOK 8192
#define K1 1024
#define N1 4096
#define K2 4160   /* 4096 (h) + 16 (probs/b2) + 48 zero-pad */
#define N2 1024

template <int V> struct ic { static constexpr int value = V; };

__device__ __forceinline__ ushort_t f2bf(float f) {
  union { float f; unsigned u; } v; v.f = f;
  unsigned u = v.u;
  u += 0x7FFFu + ((u >> 16) & 1u);   // RNE; inputs finite
  return (ushort_t)(u >> 16);
}

__device__ __forceinline__ void gload16(const void* g, void* l) {
  __builtin_amdgcn_global_load_lds((__attribute__((address_space(1))) void*)g,
                                   (__attribute__((address_space(3))) void*)l,
                                   16, 0, 0);
}

// ---------------- merged prep: wprep (blocks 0..2303) + probs (2304..4351) --
__global__ __launch_bounds__(256) void k_prep(
    const float* __restrict__ x, const float* __restrict__ node_w,
    const float* __restrict__ node_b, const float* __restrict__ w1,
    const float* __restrict__ w2, const float* __restrict__ b2,
    ushort_t* __restrict__ xb, float* __restrict__ probs,
    ushort_t* __restrict__ w1t, ushort_t* __restrict__ w2t,
    ushort_t* __restrict__ hp) {
  __shared__ ushort_t tile[64][68];
  const int b = blockIdx.x;
  if (b < 1024) {
    // w1t[l*256+h][k] = w1[l][k][h]
    const int tr = threadIdx.x >> 4, tc = (threadIdx.x & 15) * 4;
    const int l = b >> 6, rem = b & 63;
    const int kt = rem >> 2, ht = rem & 3;
    const float* in = w1 + (size_t)l * K1 * 256;
#pragma unroll
    for (int rr = 0; rr < 4; ++rr) {
      int r = tr + rr * 16;
      float4 v = *(const float4*)(in + (size_t)(kt * 64 + r) * 256 + ht * 64 + tc);
      tile[r][tc+0] = f2bf(v.x); tile[r][tc+1] = f2bf(v.y);
      tile[r][tc+2] = f2bf(v.z); tile[r][tc+3] = f2bf(v.w);
    }
    __syncthreads();
#pragma unroll
    for (int rr = 0; rr < 4; ++rr) {
      int oh = tr + rr * 16;
      ushort4 o;
      o.x = tile[tc+0][oh]; o.y = tile[tc+1][oh];
      o.z = tile[tc+2][oh]; o.w = tile[tc+3][oh];
      *(ushort4*)(w1t + (size_t)(l * 256 + ht * 64 + oh) * K1 + kt * 64 + tc) = o;
    }
  } else if (b < 2048) {
    // w2t[d][l*256+h] = w2[l][h][d]
    const int tr = threadIdx.x >> 4, tc = (threadIdx.x & 15) * 4;
    const int bb = b - 1024;
    const int l = bb >> 6, rem = bb & 63;
    const int ht = rem >> 4, dt = rem & 15;
    const float* in = w2 + (size_t)l * 256 * N2;
#pragma unroll
    for (int rr = 0; rr < 4; ++rr) {
      int r = tr + rr * 16;
      float4 v = *(const float4*)(in + (size_t)(ht * 64 + r) * N2 + dt * 64 + tc);
      tile[r][tc+0] = f2bf(v.x); tile[r][tc+1] = f2bf(v.y);
      tile[r][tc+2] = f2bf(v.z); tile[r][tc+3] = f2bf(v.w);
    }
    __syncthreads();
#pragma unroll
    for (int rr = 0; rr < 4; ++rr) {
      int od = tr + rr * 16;
      ushort4 o;
      o.x = tile[tc+0][od]; o.y = tile[tc+1][od];
      o.z = tile[tc+2][od]; o.w = tile[tc+3][od];
      *(ushort4*)(w2t + (size_t)(dt * 64 + od) * K2 + l * 256 + ht * 64 + tc) = o;
    }
  } else if (b < 2304) {
    int tid = (b - 2048) * 256 + threadIdx.x;   // 1024 * 64
    int d = tid >> 6, cc = tid & 63;
    float v = (cc < 16) ? b2[cc * N2 + d] : 0.f;
    w2t[(size_t)d * K2 + 4096 + cc] = f2bf(v);
  } else {
    // probs + x->bf16; 1 wave per token
    const int wid = threadIdx.x >> 6, lane = threadIdx.x & 63;
    const int t = (b - 2304) * 4 + wid;
    const float* xr = x + (size_t)t * K1;
    float xv[16];
#pragma unroll
    for (int j = 0; j < 4; ++j) {
      float4 v = *(const float4*)(xr + j * 256 + lane * 4);
      xv[4*j+0] = v.x; xv[4*j+1] = v.y; xv[4*j+2] = v.z; xv[4*j+3] = v.w;
    }
    ushort_t* xbr = xb + (size_t)t * K1;
#pragma unroll
    for (int j = 0; j < 4; ++j) {
      ushort4 o;
      o.x = f2bf(xv[4*j+0]); o.y = f2bf(xv[4*j+1]);
      o.z = f2bf(xv[4*j+2]); o.w = f2bf(xv[4*j+3]);
      *(ushort4*)(xbr + j * 256 + lane * 4) = o;
    }
    float c[15];
#pragma unroll
    for (int n = 0; n < 15; ++n) {
      float s = 0.f;
      const float* wr = node_w + n * K1;
#pragma unroll
      for (int j = 0; j < 4; ++j) {
        float4 w = *(const float4*)(wr + j * 256 + lane * 4);
        s += xv[4*j+0]*w.x + xv[4*j+1]*w.y + xv[4*j+2]*w.z + xv[4*j+3]*w.w;
      }
#pragma unroll
      for (int off = 32; off > 0; off >>= 1) s += __shfl_xor(s, off);
      float z = s + node_b[n];
      c[n] = 1.f / (1.f + __expf(-z));
    }
    if (lane < 16) {
      float p = 1.f;
#pragma unroll
      for (int m = 0; m < 4; ++m) {
        int jm = lane >> (4 - m);
        int node = (1 << m) - 1 + jm;
        int bit = (lane >> (3 - m)) & 1;
        p *= bit ? (1.f - c[node]) : c[node];
      }
      probs[t * 16 + lane] = p;
      hp[(size_t)t * K2 + 4096 + lane] = f2bf(p);
    }
    if (lane < 48) hp[(size_t)t * K2 + 4112 + lane] = 0;
  }
}

// ---------------- GEMM1: round-6 k_gemm8 (verified 72.8 us), unchanged -----
template <int NT, int LDA, int LDB, int BN, int MODE>
__global__ __launch_bounds__(512, 2) void k_gemm8(
    const ushort_t* __restrict__ A, const ushort_t* __restrict__ Bt,
    const float* __restrict__ probs, const float* __restrict__ b1,
    ushort_t* __restrict__ hp, float* __restrict__ out, int ntn) {
  constexpr int BHR = BN / 2;
  constexpr int WN = (BN == 256) ? 4 : 2;
  constexpr int WM = 8 / WN;
  constexpr int FH = 128 / (WM * 16);
  constexpr int ABYTES = 128 * 128;
  constexpr int BBYTES = BHR * 128;
  constexpr int KEEP = 2 + 2 * (BHR / 64);

  extern __shared__ char lds[];
  const int tid = threadIdx.x;
  int bid = blockIdx.x;
  const int nwg = gridDim.x;
  bid = (bid & 7) * (nwg >> 3) + (bid >> 3);
  const int bm = bid / ntn, bn = bid % ntn;

  const int wid = tid >> 6, lane = tid & 63;
  const int widM = wid / WN, widN = wid % WN;
  const int wmBase = widM * (FH * 16);
  const int wn = widN * 64;
  const int lr = lane & 15, g = lane >> 4;

  const ushort_t* Ag = A + (size_t)bm * 256 * LDA;
  const ushort_t* Bg = Bt + (size_t)bn * BN * LDB;

  const int srow = tid >> 3;
  const int scol = ((tid & 7) << 4) ^ ((srow & 7) << 4);

  const char* pA = (const char*)(Ag + (size_t)srow * LDA) + scol;
  const char* pB = (const char*)(Bg + (size_t)srow * LDB) + scol;

  auto stageA = [&](int buf, int half, int kt) {
    const char* src = pA + (size_t)(half * 128) * (LDA * 2) + kt * 128;
    char* dst = lds + (buf * 2 + half) * ABYTES + tid * 16;
#pragma unroll
    for (int r = 0; r < 2; ++r)
      gload16(src + (size_t)(r * 64) * (LDA * 2), dst + r * 8192);
  };
  auto stageB = [&](int buf, int half, int kt) {
    const char* src = pB + (size_t)(half * BHR) * (LDB * 2) + kt * 128;
    char* dst = lds + 4 * ABYTES + (buf * 2 + half) * BBYTES + tid * 16;
#pragma unroll
    for (int r = 0; r < BHR / 64; ++r)
      gload16(src + (size_t)(r * 64) * (LDB * 2), dst + r * 8192);
  };
  auto rdA = [&](int buf, int half, int i, int kk) -> bf16x8 {
    int r = wmBase + i * 16 + lr;
    int off = r * 128 + (((kk * 4 + g) ^ (lr & 7)) << 4);
    return *(const bf16x8*)(lds + (buf * 2 + half) * ABYTES + off);
  };
  auto rdB = [&](int buf, int j, int kk) -> bf16x8 {
    int nr = wn + j * 16;
    int half = (nr >= BHR) ? 1 : 0;
    int r = (nr & (BHR - 1)) + lr;
    int off = r * 128 + (((kk * 4 + g) ^ (lr & 7)) << 4);
    return *(const bf16x8*)(lds + 4 * ABYTES + (buf * 2 + half) * BBYTES + off);
  };

  f32x4 acc[2 * FH][4];
#pragma unroll
  for (int i = 0; i < 2 * FH; ++i)
#pragma unroll
    for (int j = 0; j < 4; ++j) acc[i][j] = (f32x4){0.f, 0.f, 0.f, 0.f};

  stageA(0, 0, 0); stageA(0, 1, 0); stageB(0, 0, 0); stageB(0, 1, 0);
  stageA(1, 0, 1); stageB(1, 0, 1); stageB(1, 1, 1);
  if constexpr (KEEP == 6) asm volatile("s_waitcnt vmcnt(6)" ::: "memory");
  else                     asm volatile("s_waitcnt vmcnt(4)" ::: "memory");
  __builtin_amdgcn_sched_barrier(0);
  __builtin_amdgcn_s_barrier();
  __builtin_amdgcn_sched_barrier(0);

  auto body = [&](auto CURC, int kt) {
    constexpr int cur = decltype(CURC)::value;
    bf16x8 bfr[2][4];
    {
      bf16x8 a0[FH][2];
#pragma unroll
      for (int kk = 0; kk < 2; ++kk) {
#pragma unroll
        for (int i = 0; i < FH; ++i) a0[i][kk] = rdA(cur, 0, i, kk);
#pragma unroll
        for (int j = 0; j < 4; ++j) bfr[kk][j] = rdB(cur, j, kk);
      }
      if (kt + 1 < NT) stageA(cur ^ 1, 1, kt + 1);
      __builtin_amdgcn_s_setprio(1);
#pragma unroll
      for (int kk = 0; kk < 2; ++kk)
#pragma unroll
        for (int j = 0; j < 4; ++j)
#pragma unroll
          for (int i = 0; i < FH; ++i)
            acc[i][j] = __builtin_amdgcn_mfma_f32_16x16x32_bf16(
                a0[i][kk], bfr[kk][j], acc[i][j], 0, 0, 0);
      __builtin_amdgcn_s_setprio(0);
    }
    __builtin_amdgcn_s_barrier();
    __builtin_amdgcn_sched_barrier(0);
    {
      bf16x8 a1[FH][2];
#pragma unroll
      for (int kk = 0; kk < 2; ++kk)
#pragma unroll
        for (int i = 0; i < FH; ++i) a1[i][kk] = rdA(cur, 1, i, kk);
      if (kt + 2 < NT) {
        stageA(cur, 0, kt + 2);
        stageB(cur, 0, kt + 2);
        stageB(cur, 1, kt + 2);
      }
      __builtin_amdgcn_s_setprio(1);
#pragma unroll
      for (int kk = 0; kk < 2; ++kk)
#pragma unroll
        for (int j = 0; j < 4; ++j)
#pragma unroll
          for (int i = 0; i < FH; ++i)
            acc[FH + i][j] = __builtin_amdgcn_mfma_f32_16x16x32_bf16(
                a1[i][kk], bfr[kk][j], acc[FH + i][j], 0, 0, 0);
      __builtin_amdgcn_s_setprio(0);
    }
    if (kt + 2 < NT) {
      if constexpr (KEEP == 6) asm volatile("s_waitcnt vmcnt(6)" ::: "memory");
      else                     asm volatile("s_waitcnt vmcnt(4)" ::: "memory");
      __builtin_amdgcn_sched_barrier(0);
    } else if (kt + 1 < NT) {
      asm volatile("s_waitcnt vmcnt(0)" ::: "memory");
      __builtin_amdgcn_sched_barrier(0);
    }
    __builtin_amdgcn_s_barrier();
    __builtin_amdgcn_sched_barrier(0);
  };

  int kt = 0;
#pragma unroll 1
  for (int it = 0; it < NT / 2; ++it) {
    body(ic<0>{}, kt); ++kt;
    body(ic<1>{}, kt); ++kt;
  }
  if constexpr (NT & 1) body(ic<0>{}, kt);

  const int rowb = bm * 256 + wmBase + g * 4;
  const int colb = bn * BN + wn + lr;
  if (MODE == 0) {
    const int leaf = bn;
#pragma unroll
    for (int q = 0; q < 2; ++q)
#pragma unroll
      for (int i = 0; i < FH; ++i) {
        int rbase = rowb + q * 128 + i * 16;
        float pm[4];
#pragma unroll
        for (int rg = 0; rg < 4; ++rg)
          pm[rg] = probs[(size_t)(rbase + rg) * 16 + leaf];
#pragma unroll
        for (int j = 0; j < 4; ++j) {
          float bias = b1[colb + j * 16];
#pragma unroll
          for (int rg = 0; rg < 4; ++rg) {
            float v = acc[q * FH + i][j][rg] + bias;
            v = v > 0.f ? v : 0.f;
            v *= pm[rg];
            hp[(size_t)(rbase + rg) * K2 + colb + j * 16] = f2bf(v);
          }
        }
      }
  } else {
#pragma unroll
    for (int q = 0; q < 2; ++q)
#pragma unroll
      for (int i = 0; i < FH; ++i) {
        int rbase = rowb + q * 128 + i * 16;
#pragma unroll
        for (int j = 0; j < 4; ++j)
#pragma unroll
          for (int rg = 0; rg < 4; ++rg)
            out[(size_t)(rbase + rg) * N2 + colb + j * 16] = acc[q * FH + i][j][rg];
      }
  }
}

// ---- GEMM2: A global->register (no A-LDS), B via 2-buf LDS, BK=64 ---------
// BM=256 BN=128, 8 waves 4Mx2N (per-wave 64x64, acc 64 VGPR). Per K-tile:
// {stage B(kt+1 -> buf^1) [2 gload_lds]; SB0; ldA(kt+1 -> reg set P^1)
// [8 plain global b128, compiler-waited before their MFMA]; SB0; rdB(buf P)
// [8 ds_reads]; 32 MFMA on aCur(P); vmcnt(8) [retires exactly B(kt+1):
// the 8 A-loads issue after it]; barrier}. A-LDS traffic eliminated:
// LDS/K-tile = 64KB reads + 16KB writes (~640cy) vs 160KB before; A comes
// from L2/L3 (hp L3-resident; both n-waves read same lines -> L1 dedup).
// Hazards: B(kt+1) overwrites B(kt-1), whose reads retired before the
// kt-1 end barrier (compiler lgkmcnt before MFMA); residency by vmcnt(8).
template <int NT>
__global__ __launch_bounds__(512, 2) void k_gemm2d(
    const ushort_t* __restrict__ A, const ushort_t* __restrict__ Bt,
    float* __restrict__ out, int ntn) {
  constexpr int BB = 128 * 128;   // bytes per B buffer
  extern __shared__ char lds[];   // 32 KB
  const int tid = threadIdx.x;
  int bid = blockIdx.x;
  const int nwg = gridDim.x;      // divisible by 8
  bid = (bid & 7) * (nwg >> 3) + (bid >> 3);
  const int bm = bid / ntn, bn = bid % ntn;

  const int wid = tid >> 6, lane = tid & 63;
  const int widM = wid >> 1, widN = wid & 1;   // 4M x 2N
  const int lr = lane & 15, g = lane >> 4;

  const ushort_t* Ag = A + (size_t)(bm * 256 + widM * 64) * K2;
  const ushort_t* Bg = Bt + (size_t)bn * 128 * K2;

  auto stageB = [&](int buf, int kt) {
#pragma unroll
    for (int r = 0; r < 2; ++r) {
      int s = tid + r * 512;
      int row = s >> 3;
      int c16 = (s & 7) ^ (row & 7);
      gload16((const char*)(Bg + (size_t)row * K2) + kt * 128 + (c16 << 4),
              lds + buf * BB + s * 16);
    }
  };
  auto rdB = [&](int buf, int nj, int kk) -> bf16x8 {
    int nr = widN * 64 + nj * 16 + lr;
    return *(const bf16x8*)(lds + buf * BB + nr * 128 +
                            (((kk * 4 + g) ^ (nr & 7)) << 4));
  };
  auto ldA = [&](bf16x8 (&dst)[4][2], int kt) {
#pragma unroll
    for (int fi = 0; fi < 4; ++fi)
#pragma unroll
      for (int kk = 0; kk < 2; ++kk)
        dst[fi][kk] = *(const bf16x8*)(
            (const char*)(Ag + (size_t)(fi * 16 + lr) * K2) +
            kt * 128 + kk * 64 + g * 16);
  };

  f32x4 acc[4][4];
#pragma unroll
  for (int i = 0; i < 4; ++i)
#pragma unroll
    for (int j = 0; j < 4; ++j) acc[i][j] = (f32x4){0.f, 0.f, 0.f, 0.f};

  bf16x8 aP[4][2], aQ[4][2];

  // prologue: B(0) [2 gloads], then A(0) [8 loads] -> vmcnt(8) retires B(0).
  stageB(0, 0);
  __builtin_amdgcn_sched_barrier(0);
  ldA(aP, 0);
  asm volatile("s_waitcnt vmcnt(8)" ::: "memory");
  __builtin_amdgcn_sched_barrier(0);
  __builtin_amdgcn_s_barrier();
  __builtin_amdgcn_sched_barrier(0);

  auto body = [&](auto PC, int kt, bf16x8 (&aCur)[4][2], bf16x8 (&aNxt)[4][2]) {
    constexpr int P = decltype(PC)::value;   // == kt & 1 == current B buf
    if (kt + 1 < NT) stageB(P ^ 1, kt + 1);
    __builtin_amdgcn_sched_barrier(0);
    if (kt + 1 < NT) ldA(aNxt, kt + 1);
    __builtin_amdgcn_sched_barrier(0);
    bf16x8 bfr[4][2];
#pragma unroll
    for (int nj = 0; nj < 4; ++nj)
#pragma unroll
      for (int kk = 0; kk < 2; ++kk) bfr[nj][kk] = rdB(P, nj, kk);
    __builtin_amdgcn_s_setprio(1);
#pragma unroll
    for (int kk = 0; kk < 2; ++kk)
#pragma unroll
      for (int nj = 0; nj < 4; ++nj)
#pragma unroll
        for (int mi = 0; mi < 4; ++mi)
          acc[mi][nj] = __builtin_amdgcn_mfma_f32_16x16x32_bf16(
              aCur[mi][kk], bfr[nj][kk], acc[mi][nj], 0, 0, 0);
    __builtin_amdgcn_s_setprio(0);
    if (kt + 1 < NT) {
      asm volatile("s_waitcnt vmcnt(8)" ::: "memory");   // B(kt+1) resident
      __builtin_amdgcn_sched_barrier(0);
      __builtin_amdgcn_s_barrier();
      __builtin_amdgcn_sched_barrier(0);
    }
  };

  int kt = 0;
#pragma unroll 1
  for (int it = 0; it < NT / 2; ++it) {
    body(ic<0>{}, kt, aP, aQ); ++kt;
    body(ic<1>{}, kt, aQ, aP); ++kt;
  }
  if constexpr (NT & 1) body(ic<0>{}, kt, aP, aQ);

  // epilogue: C/D layout col=lane&15, row=(lane>>4)*4+reg
  const int rowb = bm * 256 + widM * 64 + g * 4;
  const int colb = bn * 128 + widN * 64 + lr;
#pragma unroll
  for (int mi = 0; mi < 4; ++mi) {
    int rbase = rowb + mi * 16;
#pragma unroll
    for (int nj = 0; nj < 4; ++nj)
#pragma unroll
      for (int rg = 0; rg < 4; ++rg)
        out[(size_t)(rbase + rg) * N2 + colb + nj * 16] = acc[mi][nj][rg];
  }
}

extern "C" void kernel_launch(void* const* d_in, const int* in_sizes, int n_in,
                              void* d_out, int out_size, void* d_ws, size_t ws_size,
                              hipStream_t stream) {
  const float* x      = (const float*)d_in[0];
  const float* node_w = (const float*)d_in[1];
  const float* node_b = (const float*)d_in[2];
  const float* w1     = (const float*)d_in[3];
  const float* b1     = (const float*)d_in[4];
  const float* w2     = (const float*)d_in[5];
  const float* b2     = (const float*)d_in[6];
  float* out = (float*)d_out;

  char* ws = (char*)d_ws;
  ushort_t* xb    = (ushort_t*)(ws);
  ushort_t* w1t   = (ushort_t*)(ws + 16777216);
  ushort_t* w2t   = (ushort_t*)(ws + 25165824);
  ushort_t* hp    = (ushort_t*)(ws + 33685504);
  float*    probs = (float*)   (ws + 101842944);

  k_prep<<<4352, 256, 0, stream>>>(x, node_w, node_b, w1, w2, b2,
                                   xb, probs, w1t, w2t, hp);
  // GEMM1: 8192x4096 K=1024 (round-6 verified): 512 blocks, LDS 128 KiB
  k_gemm8<16, K1, K1, 256, 0><<<512, 512, 131072, stream>>>(
      xb, w1t, probs, b1, hp, nullptr, N1 / 256);
  // GEMM2: 8192x1024 K=4160: A-direct-to-reg, B 2-buf LDS 32 KiB, 256 blocks
  k_gemm2d<65><<<256, 512, 32768, stream>>>(hp, w2t, out, N2 / 128);
}

// Round 11
// 169.183 us; speedup vs baseline: 1.9077x; 1.4920x over previous
//
#include <hip/hip_runtime.h>
#include <stdint.h>

typedef unsigned short ushort_t;
typedef __bf16 bf16x8 __attribute__((ext_vector_type(8)));
typedef float f32x4 __attribute__((ext_vector_type(4)));

#define M_TOK 8192
#define K1 1024
#define N1 4096
#define K2 4160   /* 4096 (h) + 16 (probs/b2) + 48 zero-pad -> 65 K-steps of 64 */
#define N2 1024

template <int V> struct ic { static constexpr int value = V; };

__device__ __forceinline__ ushort_t f2bf(float f) {
  union { float f; unsigned u; } v; v.f = f;
  unsigned u = v.u;
  u += 0x7FFFu + ((u >> 16) & 1u);   // RNE; inputs finite
  return (ushort_t)(u >> 16);
}

__device__ __forceinline__ void gload16(const void* g, void* l) {
  __builtin_amdgcn_global_load_lds((__attribute__((address_space(1))) void*)g,
                                   (__attribute__((address_space(3))) void*)l,
                                   16, 0, 0);
}

// ---------------- merged prep: wprep (blocks 0..2303) + probs (2304..4351) --
__global__ __launch_bounds__(256) void k_prep(
    const float* __restrict__ x, const float* __restrict__ node_w,
    const float* __restrict__ node_b, const float* __restrict__ w1,
    const float* __restrict__ w2, const float* __restrict__ b2,
    ushort_t* __restrict__ xb, float* __restrict__ probs,
    ushort_t* __restrict__ w1t, ushort_t* __restrict__ w2t,
    ushort_t* __restrict__ hp) {
  __shared__ ushort_t tile[64][68];
  const int b = blockIdx.x;
  if (b < 1024) {
    // w1t[l*256+h][k] = w1[l][k][h]
    const int tr = threadIdx.x >> 4, tc = (threadIdx.x & 15) * 4;
    const int l = b >> 6, rem = b & 63;
    const int kt = rem >> 2, ht = rem & 3;
    const float* in = w1 + (size_t)l * K1 * 256;
#pragma unroll
    for (int rr = 0; rr < 4; ++rr) {
      int r = tr + rr * 16;
      float4 v = *(const float4*)(in + (size_t)(kt * 64 + r) * 256 + ht * 64 + tc);
      tile[r][tc+0] = f2bf(v.x); tile[r][tc+1] = f2bf(v.y);
      tile[r][tc+2] = f2bf(v.z); tile[r][tc+3] = f2bf(v.w);
    }
    __syncthreads();
#pragma unroll
    for (int rr = 0; rr < 4; ++rr) {
      int oh = tr + rr * 16;
      ushort4 o;
      o.x = tile[tc+0][oh]; o.y = tile[tc+1][oh];
      o.z = tile[tc+2][oh]; o.w = tile[tc+3][oh];
      *(ushort4*)(w1t + (size_t)(l * 256 + ht * 64 + oh) * K1 + kt * 64 + tc) = o;
    }
  } else if (b < 2048) {
    // w2t[d][l*256+h] = w2[l][h][d]
    const int tr = threadIdx.x >> 4, tc = (threadIdx.x & 15) * 4;
    const int bb = b - 1024;
    const int l = bb >> 6, rem = bb & 63;
    const int ht = rem >> 4, dt = rem & 15;
    const float* in = w2 + (size_t)l * 256 * N2;
#pragma unroll
    for (int rr = 0; rr < 4; ++rr) {
      int r = tr + rr * 16;
      float4 v = *(const float4*)(in + (size_t)(ht * 64 + r) * N2 + dt * 64 + tc);
      tile[r][tc+0] = f2bf(v.x); tile[r][tc+1] = f2bf(v.y);
      tile[r][tc+2] = f2bf(v.z); tile[r][tc+3] = f2bf(v.w);
    }
    __syncthreads();
#pragma unroll
    for (int rr = 0; rr < 4; ++rr) {
      int od = tr + rr * 16;
      ushort4 o;
      o.x = tile[tc+0][od]; o.y = tile[tc+1][od];
      o.z = tile[tc+2][od]; o.w = tile[tc+3][od];
      *(ushort4*)(w2t + (size_t)(dt * 64 + od) * K2 + l * 256 + ht * 64 + tc) = o;
    }
  } else if (b < 2304) {
    int tid = (b - 2048) * 256 + threadIdx.x;   // 1024 * 64
    int d = tid >> 6, cc = tid & 63;
    float v = (cc < 16) ? b2[cc * N2 + d] : 0.f;
    w2t[(size_t)d * K2 + 4096 + cc] = f2bf(v);
  } else {
    // probs + x->bf16; 1 wave per token
    const int wid = threadIdx.x >> 6, lane = threadIdx.x & 63;
    const int t = (b - 2304) * 4 + wid;
    const float* xr = x + (size_t)t * K1;
    float xv[16];
#pragma unroll
    for (int j = 0; j < 4; ++j) {
      float4 v = *(const float4*)(xr + j * 256 + lane * 4);
      xv[4*j+0] = v.x; xv[4*j+1] = v.y; xv[4*j+2] = v.z; xv[4*j+3] = v.w;
    }
    ushort_t* xbr = xb + (size_t)t * K1;
#pragma unroll
    for (int j = 0; j < 4; ++j) {
      ushort4 o;
      o.x = f2bf(xv[4*j+0]); o.y = f2bf(xv[4*j+1]);
      o.z = f2bf(xv[4*j+2]); o.w = f2bf(xv[4*j+3]);
      *(ushort4*)(xbr + j * 256 + lane * 4) = o;
    }
    float c[15];
#pragma unroll
    for (int n = 0; n < 15; ++n) {
      float s = 0.f;
      const float* wr = node_w + n * K1;
#pragma unroll
      for (int j = 0; j < 4; ++j) {
        float4 w = *(const float4*)(wr + j * 256 + lane * 4);
        s += xv[4*j+0]*w.x + xv[4*j+1]*w.y + xv[4*j+2]*w.z + xv[4*j+3]*w.w;
      }
#pragma unroll
      for (int off = 32; off > 0; off >>= 1) s += __shfl_xor(s, off);
      float z = s + node_b[n];
      c[n] = 1.f / (1.f + __expf(-z));
    }
    if (lane < 16) {
      float p = 1.f;
#pragma unroll
      for (int m = 0; m < 4; ++m) {
        int jm = lane >> (4 - m);
        int node = (1 << m) - 1 + jm;
        int bit = (lane >> (3 - m)) & 1;
        p *= bit ? (1.f - c[node]) : c[node];
      }
      probs[t * 16 + lane] = p;
      hp[(size_t)t * K2 + 4096 + lane] = f2bf(p);
    }
    if (lane < 48) hp[(size_t)t * K2 + 4112 + lane] = 0;
  }
}

// ---------------- 256xBN MFMA GEMM, 2 barriers/K-tile, K-loop unroll x2 -----
// (round-6 verified config: GEMM1 72.8us, GEMM2 72.4us, conflicts 0)
template <int NT, int LDA, int LDB, int BN, int MODE>
__global__ __launch_bounds__(512, 2) void k_gemm8(
    const ushort_t* __restrict__ A, const ushort_t* __restrict__ Bt,
    const float* __restrict__ probs, const float* __restrict__ b1,
    ushort_t* __restrict__ hp, float* __restrict__ out, int ntn) {
  constexpr int BHR = BN / 2;                 // B half rows
  constexpr int WN = (BN == 256) ? 4 : 2;
  constexpr int WM = 8 / WN;
  constexpr int FH = 128 / (WM * 16);         // m-frags per half per wave
  constexpr int ABYTES = 128 * 128;
  constexpr int BBYTES = BHR * 128;
  constexpr int KEEP = 2 + 2 * (BHR / 64);    // region1 loads: A0 + B0 + B1

  extern __shared__ char lds[];
  const int tid = threadIdx.x;
  int bid = blockIdx.x;
  const int nwg = gridDim.x;                  // divisible by 8
  bid = (bid & 7) * (nwg >> 3) + (bid >> 3);  // XCD swizzle (bijective)
  const int bm = bid / ntn, bn = bid % ntn;

  const int wid = tid >> 6, lane = tid & 63;
  const int widM = wid / WN, widN = wid % WN;
  const int wmBase = widM * (FH * 16);
  const int wn = widN * 64;
  const int lr = lane & 15, g = lane >> 4;

  const ushort_t* Ag = A + (size_t)bm * 256 * LDA;
  const ushort_t* Bg = Bt + (size_t)bn * BN * LDB;

  const int srow = tid >> 3;
  const int scol = ((tid & 7) << 4) ^ ((srow & 7) << 4);

  const char* pA = (const char*)(Ag + (size_t)srow * LDA) + scol;
  const char* pB = (const char*)(Bg + (size_t)srow * LDB) + scol;

  auto stageA = [&](int buf, int half, int kt) {
    const char* src = pA + (size_t)(half * 128) * (LDA * 2) + kt * 128;
    char* dst = lds + (buf * 2 + half) * ABYTES + tid * 16;
#pragma unroll
    for (int r = 0; r < 2; ++r)
      gload16(src + (size_t)(r * 64) * (LDA * 2), dst + r * 8192);
  };
  auto stageB = [&](int buf, int half, int kt) {
    const char* src = pB + (size_t)(half * BHR) * (LDB * 2) + kt * 128;
    char* dst = lds + 4 * ABYTES + (buf * 2 + half) * BBYTES + tid * 16;
#pragma unroll
    for (int r = 0; r < BHR / 64; ++r)
      gload16(src + (size_t)(r * 64) * (LDB * 2), dst + r * 8192);
  };
  auto rdA = [&](int buf, int half, int i, int kk) -> bf16x8 {
    int r = wmBase + i * 16 + lr;
    int off = r * 128 + (((kk * 4 + g) ^ (lr & 7)) << 4);
    return *(const bf16x8*)(lds + (buf * 2 + half) * ABYTES + off);
  };
  auto rdB = [&](int buf, int j, int kk) -> bf16x8 {
    int nr = wn + j * 16;
    int half = (nr >= BHR) ? 1 : 0;
    int r = (nr & (BHR - 1)) + lr;
    int off = r * 128 + (((kk * 4 + g) ^ (lr & 7)) << 4);
    return *(const bf16x8*)(lds + 4 * ABYTES + (buf * 2 + half) * BBYTES + off);
  };

  f32x4 acc[2 * FH][4];
#pragma unroll
  for (int i = 0; i < 2 * FH; ++i)
#pragma unroll
    for (int j = 0; j < 4; ++j) acc[i][j] = (f32x4){0.f, 0.f, 0.f, 0.f};

  // prologue: buf0 full (oldest), then buf1 {A0,B0,B1}.
  stageA(0, 0, 0); stageA(0, 1, 0); stageB(0, 0, 0); stageB(0, 1, 0);
  stageA(1, 0, 1); stageB(1, 0, 1); stageB(1, 1, 1);
  if constexpr (KEEP == 6) asm volatile("s_waitcnt vmcnt(6)" ::: "memory");
  else                     asm volatile("s_waitcnt vmcnt(4)" ::: "memory");
  __builtin_amdgcn_sched_barrier(0);
  __builtin_amdgcn_s_barrier();
  __builtin_amdgcn_sched_barrier(0);

  auto body = [&](auto CURC, int kt) {
    constexpr int cur = decltype(CURC)::value;
    bf16x8 bfr[2][4];
    // ---------------- region 0 (A half 0, all B) ----------------
    {
      bf16x8 a0[FH][2];
#pragma unroll
      for (int kk = 0; kk < 2; ++kk) {
#pragma unroll
        for (int i = 0; i < FH; ++i) a0[i][kk] = rdA(cur, 0, i, kk);
#pragma unroll
        for (int j = 0; j < 4; ++j) bfr[kk][j] = rdB(cur, j, kk);
      }
      if (kt + 1 < NT) stageA(cur ^ 1, 1, kt + 1);
      __builtin_amdgcn_s_setprio(1);
#pragma unroll
      for (int kk = 0; kk < 2; ++kk)
#pragma unroll
        for (int j = 0; j < 4; ++j)
#pragma unroll
          for (int i = 0; i < FH; ++i)
            acc[i][j] = __builtin_amdgcn_mfma_f32_16x16x32_bf16(
                a0[i][kk], bfr[kk][j], acc[i][j], 0, 0, 0);
      __builtin_amdgcn_s_setprio(0);
    }
    __builtin_amdgcn_s_barrier();
    __builtin_amdgcn_sched_barrier(0);
    // ---------------- region 1 (A half 1, reuse bfr) ----------------
    {
      bf16x8 a1[FH][2];
#pragma unroll
      for (int kk = 0; kk < 2; ++kk)
#pragma unroll
        for (int i = 0; i < FH; ++i) a1[i][kk] = rdA(cur, 1, i, kk);
      if (kt + 2 < NT) {
        stageA(cur, 0, kt + 2);
        stageB(cur, 0, kt + 2);
        stageB(cur, 1, kt + 2);
      }
      __builtin_amdgcn_s_setprio(1);
#pragma unroll
      for (int kk = 0; kk < 2; ++kk)
#pragma unroll
        for (int j = 0; j < 4; ++j)
#pragma unroll
          for (int i = 0; i < FH; ++i)
            acc[FH + i][j] = __builtin_amdgcn_mfma_f32_16x16x32_bf16(
                a1[i][kk], bfr[kk][j], acc[FH + i][j], 0, 0, 0);
      __builtin_amdgcn_s_setprio(0);
    }
    if (kt + 2 < NT) {
      if constexpr (KEEP == 6) asm volatile("s_waitcnt vmcnt(6)" ::: "memory");
      else                     asm volatile("s_waitcnt vmcnt(4)" ::: "memory");
      __builtin_amdgcn_sched_barrier(0);
    } else if (kt + 1 < NT) {
      asm volatile("s_waitcnt vmcnt(0)" ::: "memory");
      __builtin_amdgcn_sched_barrier(0);
    }
    __builtin_amdgcn_s_barrier();
    __builtin_amdgcn_sched_barrier(0);
  };

  int kt = 0;
#pragma unroll 1
  for (int it = 0; it < NT / 2; ++it) {
    body(ic<0>{}, kt); ++kt;
    body(ic<1>{}, kt); ++kt;
  }
  if constexpr (NT & 1) body(ic<0>{}, kt);

  // epilogue: C/D layout col=lane&15, row=(lane>>4)*4+reg
  const int rowb = bm * 256 + wmBase + g * 4;
  const int colb = bn * BN + wn + lr;
  if (MODE == 0) {
    const int leaf = bn;   // BN=256 tile == one leaf
#pragma unroll
    for (int q = 0; q < 2; ++q)
#pragma unroll
      for (int i = 0; i < FH; ++i) {
        int rbase = rowb + q * 128 + i * 16;
        float pm[4];
#pragma unroll
        for (int rg = 0; rg < 4; ++rg)
          pm[rg] = probs[(size_t)(rbase + rg) * 16 + leaf];
#pragma unroll
        for (int j = 0; j < 4; ++j) {
          float bias = b1[colb + j * 16];
#pragma unroll
          for (int rg = 0; rg < 4; ++rg) {
            float v = acc[q * FH + i][j][rg] + bias;
            v = v > 0.f ? v : 0.f;
            v *= pm[rg];
            hp[(size_t)(rbase + rg) * K2 + colb + j * 16] = f2bf(v);
          }
        }
      }
  } else {
#pragma unroll
    for (int q = 0; q < 2; ++q)
#pragma unroll
      for (int i = 0; i < FH; ++i) {
        int rbase = rowb + q * 128 + i * 16;
#pragma unroll
        for (int j = 0; j < 4; ++j)
#pragma unroll
          for (int rg = 0; rg < 4; ++rg)
            out[(size_t)(rbase + rg) * N2 + colb + j * 16] = acc[q * FH + i][j][rg];
      }
  }
}

extern "C" void kernel_launch(void* const* d_in, const int* in_sizes, int n_in,
                              void* d_out, int out_size, void* d_ws, size_t ws_size,
                              hipStream_t stream) {
  const float* x      = (const float*)d_in[0];
  const float* node_w = (const float*)d_in[1];
  const float* node_b = (const float*)d_in[2];
  const float* w1     = (const float*)d_in[3];
  const float* b1     = (const float*)d_in[4];
  const float* w2     = (const float*)d_in[5];
  const float* b2     = (const float*)d_in[6];
  float* out = (float*)d_out;

  char* ws = (char*)d_ws;
  ushort_t* xb    = (ushort_t*)(ws);
  ushort_t* w1t   = (ushort_t*)(ws + 16777216);
  ushort_t* w2t   = (ushort_t*)(ws + 25165824);
  ushort_t* hp    = (ushort_t*)(ws + 33685504);
  float*    probs = (float*)   (ws + 101842944);

  k_prep<<<4352, 256, 0, stream>>>(x, node_w, node_b, w1, w2, b2,
                                   xb, probs, w1t, w2t, hp);
  // GEMM1: 8192x4096, K=1024: 32x16=512 blocks, BN=256, LDS 128 KiB
  k_gemm8<16, K1, K1, 256, 0><<<512, 512, 131072, stream>>>(
      xb, w1t, probs, b1, hp, nullptr, N1 / 256);
  // GEMM2: 8192x1024, K=4160: 32x8=256 blocks, BN=128, LDS 96 KiB
  k_gemm8<65, K2, K2, 128, 1><<<256, 512, 98304, stream>>>(
      hp, w2t, nullptr, nullptr, nullptr, out, N2 / 128);
}